// Round 16
// baseline (68.836 us; speedup 1.0000x reference)
//
#include <hip/hip_runtime.h>
#include <stdint.h>

typedef unsigned short u16;
typedef __attribute__((ext_vector_type(8))) short short8;
typedef __attribute__((ext_vector_type(4))) float f32x4;

#define MFMA16(a, b, c) __builtin_amdgcn_mfma_f32_16x16x32_bf16((a), (b), (c), 0, 0, 0)

__device__ __forceinline__ u16 f2bf(float f) {
  unsigned int u = __float_as_uint(f);
  u += 0x7FFFu + ((u >> 16) & 1u);
  return (u16)(u >> 16);
}

__device__ __forceinline__ void gload16(const void* g, u16* lds) {
  __builtin_amdgcn_global_load_lds(
      (const __attribute__((address_space(1))) unsigned int*)g,
      (__attribute__((address_space(3))) unsigned int*)lds, 16, 0, 0);
}

// ---------------- prep: input cvt + all 4 weight transposes, ONE launch ------
__global__ void prep_all(const float* __restrict__ x, u16* __restrict__ xb, int n4x,
                         const float* __restrict__ cx, u16* __restrict__ cb, int n4c,
                         const float* __restrict__ Wq, const float* __restrict__ Wk,
                         const float* __restrict__ Wv, const float* __restrict__ Wo,
                         u16* __restrict__ wqT, u16* __restrict__ wkvT,
                         u16* __restrict__ woT) {
  __shared__ float tile[32][33];
  int z = blockIdx.z;
  int tx = threadIdx.x, ty = threadIdx.y;  // block (32,8)
  if (z == 4) {
    int bid = blockIdx.y * 32 + blockIdx.x;   // [0,1024)
    int tid = ty * 32 + tx;                   // [0,256)
    int idx = bid * 256 + tid, stride = 1024 * 256;
    int total = n4x + n4c;
    for (int i2 = idx; i2 < total; i2 += stride) {
      float4 v = (i2 < n4x) ? ((const float4*)x)[i2] : ((const float4*)cx)[i2 - n4x];
      ushort4 o;
      o.x = f2bf(v.x); o.y = f2bf(v.y); o.z = f2bf(v.z); o.w = f2bf(v.w);
      if (i2 < n4x) ((ushort4*)xb)[i2] = o; else ((ushort4*)cb)[i2 - n4x] = o;
    }
    return;
  }
  const float* src; u16* dst; int R, C; float scale = 1.0f;
  if (z == 0)      { src = Wq; dst = wqT;  R = 1024; C = 512;  scale = 0.125f; }
  else if (z == 1) { src = Wk; dst = wkvT; R = 768;  C = 512;  }
  else if (z == 2) { src = Wv; dst = wkvT + (size_t)512 * 768; R = 768; C = 512; }
  else             { src = Wo; dst = woT;  R = 512;  C = 1024; }
  int bx = blockIdx.x * 32, by = blockIdx.y * 32;
  if (bx >= C || by >= R) return;
#pragma unroll
  for (int i = 0; i < 4; ++i)
    tile[ty + 8 * i][tx] = src[(size_t)(by + ty + 8 * i) * C + bx + tx];
  __syncthreads();
#pragma unroll
  for (int i = 0; i < 4; ++i)
    dst[(size_t)(bx + ty + 8 * i) * R + by + tx] = f2bf(tile[tx][ty + 8 * i] * scale);
}

// ---------------- GEMM body (r14 single-buffered, proven) -------------------
// 128x64 tile, BK=64, 256 threads (4 waves 2Mx2N). 16 MFMA/wave per K-step.
// A and B bf16 via async global_load_lds, involutive XOR swizzle (cg ^= row&7).
// MODE 0: f32 row-major (needs N). MODE 1: bf16 per-head Q [bh][2048][64].
// MODE 2: KV split: tn<512 -> K [bh][512][64]; else V transposed -> vtb [bh][64][512].
template <int MODE>
__device__ __forceinline__ void gemm_body(const u16* __restrict__ A,
                                          const u16* __restrict__ BT,
                                          void* __restrict__ C0p,
                                          void* __restrict__ C1p,
                                          int tm, int tn, int K, int N, u16* smem) {
  u16* As = smem;          // [128][64] (col-groups pre-swizzled per row)
  u16* Bs = smem + 8192;   // [64][64]
  const int t = threadIdx.x;
  const int w = t >> 6, l = t & 63, lr = l & 15, lg = l >> 4;
  const int wr = w >> 1, wc = w & 1;

  f32x4 acc[4][2];
#pragma unroll
  for (int mi = 0; mi < 4; ++mi)
#pragma unroll
    for (int ni = 0; ni < 2; ++ni) acc[mi][ni] = (f32x4){0.f, 0.f, 0.f, 0.f};

  for (int kt = 0; kt < K; kt += 64) {
#pragma unroll
    for (int p = 0; p < 4; ++p) {
      int idx = p * 256 + t, row = idx >> 3, cg = idx & 7;
      gload16(A + (size_t)(tm + row) * K + kt + ((cg ^ (row & 7)) * 8),
              As + (p * 256 + (t & 192)) * 8);
    }
#pragma unroll
    for (int pb = 0; pb < 2; ++pb) {
      int idx = pb * 256 + t, row = idx >> 3, cg = idx & 7;
      gload16(BT + (size_t)(tn + row) * K + kt + ((cg ^ (row & 7)) * 8),
              Bs + (pb * 256 + (t & 192)) * 8);
    }
    __syncthreads();
    short8 af[4][2], bf[2][2];
#pragma unroll
    for (int mi = 0; mi < 4; ++mi)
#pragma unroll
      for (int kk = 0; kk < 2; ++kk)
        af[mi][kk] = *(const short8*)
            &As[(wr * 64 + mi * 16 + lr) * 64 + (((kk * 4 + lg) ^ (lr & 7)) * 8)];
#pragma unroll
    for (int ni = 0; ni < 2; ++ni)
#pragma unroll
      for (int kk = 0; kk < 2; ++kk)
        bf[ni][kk] = *(const short8*)
            &Bs[(wc * 32 + ni * 16 + lr) * 64 + (((kk * 4 + lg) ^ (lr & 7)) * 8)];
#pragma unroll
    for (int mi = 0; mi < 4; ++mi)
#pragma unroll
      for (int ni = 0; ni < 2; ++ni) {
        acc[mi][ni] = MFMA16(af[mi][0], bf[ni][0], acc[mi][ni]);
        acc[mi][ni] = MFMA16(af[mi][1], bf[ni][1], acc[mi][ni]);
      }
    __syncthreads();
  }

  if (MODE == 2 && tn >= 512) {
    // V: LDS-transpose the 128(j) x 64(c) tile, write vtb [bh][c=64][j=512].
    u16* tile = smem;  // [64][136]
#pragma unroll
    for (int mi = 0; mi < 4; ++mi)
#pragma unroll
      for (int ni = 0; ni < 2; ++ni) {
        ushort4 pk;
        pk.x = f2bf(acc[mi][ni][0]); pk.y = f2bf(acc[mi][ni][1]);
        pk.z = f2bf(acc[mi][ni][2]); pk.w = f2bf(acc[mi][ni][3]);
        *(ushort4*)&tile[(wc * 32 + ni * 16 + lr) * 136 + wr * 64 + mi * 16 + lg * 4] = pk;
      }
    __syncthreads();
    int bh = ((tm >> 9) << 3) + ((tn - 512) >> 6);
    u16* dst = (u16*)C1p + (size_t)bh * 64 * 512 + (tm & 511);
#pragma unroll
    for (int p = 0; p < 4; ++p) {
      int c = (p * 256 + t) >> 4, jj = (t & 15) * 8;
      short8 v = *(const short8*)&tile[c * 136 + jj];
      *(short8*)(dst + (size_t)c * 512 + jj) = v;
    }
    return;
  }

#pragma unroll
  for (int mi = 0; mi < 4; ++mi)
#pragma unroll
    for (int ni = 0; ni < 2; ++ni)
#pragma unroll
      for (int r = 0; r < 4; ++r) {
        int rg = tm + wr * 64 + mi * 16 + lg * 4 + r;
        int cg = tn + wc * 32 + ni * 16 + lr;
        float val = acc[mi][ni][r];
        if (MODE == 0) {
          ((float*)C0p)[(size_t)rg * N + cg] = val;
        } else if (MODE == 1) {
          ((u16*)C0p)[(((size_t)(rg >> 11) * 8 + (cg >> 6)) * 2048 + (rg & 2047)) * 64 +
                      (cg & 63)] = f2bf(val);
        } else {
          ((u16*)C0p)[(((size_t)(rg >> 9) * 8 + (cg >> 6)) * 512 + (rg & 511)) * 64 +
                      (cg & 63)] = f2bf(val);
        }
      }
}

// Fused Q + KV projection GEMM (bf16 inputs). 768 blocks: [0,512) Q, [512,768) KV.
__global__ __launch_bounds__(256) void gemm_qkv(const u16* __restrict__ xb,
                                                const u16* __restrict__ wqT,
                                                u16* __restrict__ qhb,
                                                const u16* __restrict__ cb,
                                                const u16* __restrict__ wkvT,
                                                u16* __restrict__ khb,
                                                u16* __restrict__ vtb) {
  __shared__ __align__(16) u16 smem[12288];
  int gid = (int)blockIdx.x;
  gid = (gid & 7) * 96 + (gid >> 3);  // XCD-bijective swizzle (768 % 8 == 0)
  if (gid < 512) {
    gemm_body<1>(xb, wqT, qhb, nullptr, (gid >> 3) * 128, (gid & 7) * 64, 1024, 512, smem);
  } else {
    int g2 = gid - 512;
    gemm_body<2>(cb, wkvT, khb, vtb, (g2 >> 4) * 128, (g2 & 15) * 64, 768, 1024, smem);
  }
}

// Output projection GEMM. 1024 blocks.
__global__ __launch_bounds__(256) void gemm_o(const u16* __restrict__ aob,
                                              const u16* __restrict__ woT,
                                              float* __restrict__ out) {
  __shared__ __align__(16) u16 smem[12288];
  int gid = (int)blockIdx.x;
  gid = (gid & 7) * 128 + (gid >> 3);  // XCD-bijective swizzle (1024 % 8 == 0)
  gemm_body<0>(aob, woT, out, nullptr, (gid >> 4) * 128, (gid & 15) * 64, 512, 1024, smem);
}

// ---------------- attention (r14 + counted-vmcnt + setprio) ----------------
// 512 blocks x 512 threads (8 waves, 16 q-rows each = 128 rows/block).
// T4: K loads (8) then V loads (8) issued back-to-back; raw s_barrier with
// vmcnt(8) waits K only -> QK^T and the register softmax run while V's 64KB
// drains in background; vmcnt(0)+barrier before PV. T5: setprio around MFMA
// clusters (waves are barrier-free/independent after staging = m191 regime).
// Math byte-identical to the verified r12/r14 kernel.
__global__ __launch_bounds__(512, 2) void attn_kernel(const u16* __restrict__ qhb,
                                                      const u16* __restrict__ khb,
                                                      const u16* __restrict__ vtb,
                                                      u16* __restrict__ aob) {
  __shared__ __align__(16) u16 kb[512 * 64];     // K  [512 j][64 c]
  __shared__ __align__(16) u16 vb[64 * 512];     // V^T [64 c][512 j]
  __shared__ __align__(16) u16 pl[8][16 * 64];   // per-wave P window [16 i][64 j]
  const int t = threadIdx.x, w = t >> 6, l = t & 63, i = l & 15, g = l >> 4;
  int lid = (int)blockIdx.x;
  lid = (lid & 7) * 64 + (lid >> 3);  // XCD-bijective swizzle (512 % 8 == 0)
  const int bh = lid >> 4, qh = lid & 15;
  const int i7 = i & 7;
  const int row0 = qh * 128 + w * 16;

  const u16* qp = qhb + ((size_t)bh * 2048 + row0) * 64;
  const u16* kp = khb + (size_t)bh * 512 * 64;
  const u16* vp = vtb + (size_t)bh * 64 * 512;

  short8 qa0 = *(const short8*)(qp + (size_t)i * 64 + g * 8);
  short8 qa1 = *(const short8*)(qp + (size_t)i * 64 + 32 + g * 8);

  const int wbase = (t & 448) * 8;  // wave-uniform LDS chunk base (u16 units)

  // ---- issue K loads (8/thread) then V loads (8/thread) ----
#pragma unroll
  for (int p = 0; p < 8; ++p) {
    int s = p * 512 + t;
    int r = s >> 3, cg = s & 7;
    gload16(kp + (size_t)r * 64 + ((cg ^ (r & 7)) * 8), kb + p * 4096 + wbase);
  }
#pragma unroll
  for (int p = 0; p < 8; ++p) {
    int s = p * 512 + t;
    int r = s >> 6, cg = s & 63;
    gload16(vp + (size_t)r * 512 + ((cg ^ (r & 7)) * 8), vb + p * 4096 + wbase);
  }
  // T4: wait only the 8 oldest (K) loads; V's 8 stay in flight across barrier.
  asm volatile("s_waitcnt vmcnt(8)" ::: "memory");
  __builtin_amdgcn_s_barrier();

  // ---- QK^T: all 32 j-tiles, barrier-free (V drains underneath) ----
  f32x4 sc[32];
#pragma unroll
  for (int jt = 0; jt < 32; ++jt) {
    int r = jt * 16 + i;
    short8 k0 = *(const short8*)&kb[r * 64 + ((g ^ i7) * 8)];
    short8 k1 = *(const short8*)&kb[r * 64 + (((4 + g) ^ i7) * 8)];
    f32x4 a = (f32x4){0.f, 0.f, 0.f, 0.f};
    __builtin_amdgcn_s_setprio(1);
    a = MFMA16(k0, qa0, a);
    a = MFMA16(k1, qa1, a);
    __builtin_amdgcn_s_setprio(0);
    sc[jt] = a;
  }

  // ---- softmax (register-only; V still draining) ----
  f32x4 vm = sc[0];
#pragma unroll
  for (int jt = 1; jt < 32; ++jt) {
#pragma unroll
    for (int r = 0; r < 4; ++r) vm[r] = fmaxf(vm[r], sc[jt][r]);
  }
  float mx = fmaxf(fmaxf(vm[0], vm[1]), fmaxf(vm[2], vm[3]));
  mx = fmaxf(mx, __shfl_xor(mx, 16));
  mx = fmaxf(mx, __shfl_xor(mx, 32));
  float sum = 0.f;
#pragma unroll
  for (int jt = 0; jt < 32; ++jt) {
#pragma unroll
    for (int r = 0; r < 4; ++r) {
      float e = __expf(sc[jt][r] - mx);
      sc[jt][r] = e;
      sum += e;
    }
  }
  sum += __shfl_xor(sum, 16);
  sum += __shfl_xor(sum, 32);
  float inv = 1.f / sum;

  // T4: drain V, sync -> vb ready for all waves.
  asm volatile("s_waitcnt vmcnt(0)" ::: "memory");
  __builtin_amdgcn_s_barrier();

  // ---- PV: 8 chunks x 2 T-steps, barrier-free (pl wave-private) ----
  u16* pw = pl[w];
  f32x4 oac[4];
#pragma unroll
  for (int ct = 0; ct < 4; ++ct) oac[ct] = (f32x4){0.f, 0.f, 0.f, 0.f};

#pragma unroll
  for (int c8 = 0; c8 < 8; ++c8) {
#pragma unroll
    for (int tt = 0; tt < 4; ++tt) {
      int jt = c8 * 4 + tt;
      unsigned w0, w1;
      asm("v_cvt_pk_bf16_f32 %0, %1, %2" : "=v"(w0) : "v"(sc[jt][0]), "v"(sc[jt][1]));
      asm("v_cvt_pk_bf16_f32 %0, %1, %2" : "=v"(w1) : "v"(sc[jt][2]), "v"(sc[jt][3]));
      uint2 pk2; pk2.x = w0; pk2.y = w1;
      *(uint2*)&pw[i * 64 + ((tt * 16 + g * 4) ^ (i7 * 8))] = pk2;
    }
    asm volatile("s_waitcnt lgkmcnt(0)" ::: "memory");
    __builtin_amdgcn_sched_barrier(0);
#pragma unroll
    for (int T2 = 0; T2 < 2; ++T2) {
      short8 pa = *(const short8*)&pw[i * 64 + ((T2 * 32 + g * 8) ^ (i7 * 8))];
      int jg = c8 * 8 + T2 * 4 + g;  // global j-group 0..63
      __builtin_amdgcn_s_setprio(1);
#pragma unroll
      for (int ct = 0; ct < 4; ++ct) {
        int vr = ct * 16 + i;
        short8 vf = *(const short8*)&vb[vr * 512 + ((jg ^ (vr & 7)) * 8)];
        oac[ct] = MFMA16(pa, vf, oac[ct]);
      }
      __builtin_amdgcn_s_setprio(0);
    }
    asm volatile("" ::: "memory");  // WAR: reads done before next chunk's stores
  }

  // epilogue: redistribute 1/sum to the lanes holding each output row, store.
  float iv[4];
#pragma unroll
  for (int r = 0; r < 4; ++r) iv[r] = __shfl(inv, (l & 48) + g * 4 + r);
  u16* op = aob + ((size_t)(bh >> 3) * 2048 + row0) * 512 + (bh & 7) * 64;
#pragma unroll
  for (int ct = 0; ct < 4; ++ct)
#pragma unroll
    for (int r = 0; r < 4; ++r)
      op[(size_t)(g * 4 + r) * 512 + ct * 16 + i] = f2bf(oac[ct][r] * iv[r]);
}

// ---------------- launch ----------------
extern "C" void kernel_launch(void* const* d_in, const int* in_sizes, int n_in,
                              void* d_out, int out_size, void* d_ws, size_t ws_size,
                              hipStream_t stream) {
  const float* x  = (const float*)d_in[0];  // [4,2048,1024]
  const float* cx = (const float*)d_in[1];  // [4,512,768]
  const float* Wq = (const float*)d_in[2];  // [1024,512]
  const float* Wk = (const float*)d_in[3];  // [768,512]
  const float* Wv = (const float*)d_in[4];  // [768,512]
  const float* Wo = (const float*)d_in[5];  // [512,1024]
  float* out = (float*)d_out;               // [4,2048,1024]

  char* p = (char*)d_ws;
  u16* xb   = (u16*)p; p += (size_t)8388608 * 2;   // x bf16
  u16* cb   = (u16*)p; p += (size_t)1572864 * 2;   // context bf16
  u16* wqT  = (u16*)p; p += (size_t)524288 * 2;    // Wq^T * 0.125   [512][1024]
  u16* wkvT = (u16*)p; p += (size_t)786432 * 2;    // [Wk^T; Wv^T]   [1024][768]
  u16* woT  = (u16*)p; p += (size_t)524288 * 2;    // Wo^T           [1024][512]
  u16* qhb  = (u16*)p; p += (size_t)4194304 * 2;   // q   [bh][2048][64]
  u16* khb  = (u16*)p; p += (size_t)1048576 * 2;   // k   [bh][512][64]
  u16* vtb  = (u16*)p; p += (size_t)1048576 * 2;   // v^T [bh][64][512]
  u16* aob  = (u16*)p; p += (size_t)4194304 * 2;   // attn out [8192][512]

  prep_all<<<dim3(32, 32, 5), dim3(32, 8), 0, stream>>>(
      x, xb, 8388608 / 4, cx, cb, 1572864 / 4, Wq, Wk, Wv, Wo, wqT, wkvT, woT);
  gemm_qkv<<<768, 256, 0, stream>>>(xb, wqT, qhb, cb, wkvT, khb, vtb);
  attn_kernel<<<512, 512, 0, stream>>>(qhb, khb, vtb, aob);
  gemm_o<<<1024, 256, 0, stream>>>(aob, woT, out);
}

// Round 17
// 67.410 us; speedup vs baseline: 1.0212x; 1.0212x over previous
//
#include <hip/hip_runtime.h>
#include <stdint.h>

typedef unsigned short u16;
typedef __attribute__((ext_vector_type(8))) short short8;
typedef __attribute__((ext_vector_type(4))) float f32x4;

#define MFMA16(a, b, c) __builtin_amdgcn_mfma_f32_16x16x32_bf16((a), (b), (c), 0, 0, 0)

__device__ __forceinline__ u16 f2bf(float f) {
  unsigned int u = __float_as_uint(f);
  u += 0x7FFFu + ((u >> 16) & 1u);
  return (u16)(u >> 16);
}

__device__ __forceinline__ void gload16(const void* g, u16* lds) {
  __builtin_amdgcn_global_load_lds(
      (const __attribute__((address_space(1))) unsigned int*)g,
      (__attribute__((address_space(3))) unsigned int*)lds, 16, 0, 0);
}

// ---------------- prep: input cvt + all 4 weight transposes, ONE launch ------
__global__ void prep_all(const float* __restrict__ x, u16* __restrict__ xb, int n4x,
                         const float* __restrict__ cx, u16* __restrict__ cb, int n4c,
                         const float* __restrict__ Wq, const float* __restrict__ Wk,
                         const float* __restrict__ Wv, const float* __restrict__ Wo,
                         u16* __restrict__ wqT, u16* __restrict__ wkvT,
                         u16* __restrict__ woT) {
  __shared__ float tile[32][33];
  int z = blockIdx.z;
  int tx = threadIdx.x, ty = threadIdx.y;  // block (32,8)
  if (z == 4) {
    int bid = blockIdx.y * 32 + blockIdx.x;   // [0,1024)
    int tid = ty * 32 + tx;                   // [0,256)
    int idx = bid * 256 + tid, stride = 1024 * 256;
    int total = n4x + n4c;
    for (int i2 = idx; i2 < total; i2 += stride) {
      float4 v = (i2 < n4x) ? ((const float4*)x)[i2] : ((const float4*)cx)[i2 - n4x];
      ushort4 o;
      o.x = f2bf(v.x); o.y = f2bf(v.y); o.z = f2bf(v.z); o.w = f2bf(v.w);
      if (i2 < n4x) ((ushort4*)xb)[i2] = o; else ((ushort4*)cb)[i2 - n4x] = o;
    }
    return;
  }
  const float* src; u16* dst; int R, C; float scale = 1.0f;
  if (z == 0)      { src = Wq; dst = wqT;  R = 1024; C = 512;  scale = 0.125f; }
  else if (z == 1) { src = Wk; dst = wkvT; R = 768;  C = 512;  }
  else if (z == 2) { src = Wv; dst = wkvT + (size_t)512 * 768; R = 768; C = 512; }
  else             { src = Wo; dst = woT;  R = 512;  C = 1024; }
  int bx = blockIdx.x * 32, by = blockIdx.y * 32;
  if (bx >= C || by >= R) return;
#pragma unroll
  for (int i = 0; i < 4; ++i)
    tile[ty + 8 * i][tx] = src[(size_t)(by + ty + 8 * i) * C + bx + tx];
  __syncthreads();
#pragma unroll
  for (int i = 0; i < 4; ++i)
    dst[(size_t)(bx + ty + 8 * i) * R + by + tx] = f2bf(tile[tx][ty + 8 * i] * scale);
}

// ---------------- GEMM body (r14 single-buffered, proven) -------------------
// 128x64 tile, BK=64, 256 threads (4 waves 2Mx2N). 16 MFMA/wave per K-step.
// A and B bf16 via async global_load_lds, involutive XOR swizzle (cg ^= row&7).
// MODE 1: bf16 per-head Q [bh][2048][64].
// MODE 2: KV split: tn<512 -> K [bh][512][64]; else V transposed -> vtb [bh][64][512].
template <int MODE>
__device__ __forceinline__ void gemm_body(const u16* __restrict__ A,
                                          const u16* __restrict__ BT,
                                          void* __restrict__ C0p,
                                          void* __restrict__ C1p,
                                          int tm, int tn, int K, int N, u16* smem) {
  u16* As = smem;          // [128][64] (col-groups pre-swizzled per row)
  u16* Bs = smem + 8192;   // [64][64]
  const int t = threadIdx.x;
  const int w = t >> 6, l = t & 63, lr = l & 15, lg = l >> 4;
  const int wr = w >> 1, wc = w & 1;

  f32x4 acc[4][2];
#pragma unroll
  for (int mi = 0; mi < 4; ++mi)
#pragma unroll
    for (int ni = 0; ni < 2; ++ni) acc[mi][ni] = (f32x4){0.f, 0.f, 0.f, 0.f};

  for (int kt = 0; kt < K; kt += 64) {
#pragma unroll
    for (int p = 0; p < 4; ++p) {
      int idx = p * 256 + t, row = idx >> 3, cg = idx & 7;
      gload16(A + (size_t)(tm + row) * K + kt + ((cg ^ (row & 7)) * 8),
              As + (p * 256 + (t & 192)) * 8);
    }
#pragma unroll
    for (int pb = 0; pb < 2; ++pb) {
      int idx = pb * 256 + t, row = idx >> 3, cg = idx & 7;
      gload16(BT + (size_t)(tn + row) * K + kt + ((cg ^ (row & 7)) * 8),
              Bs + (pb * 256 + (t & 192)) * 8);
    }
    __syncthreads();
    short8 af[4][2], bf[2][2];
#pragma unroll
    for (int mi = 0; mi < 4; ++mi)
#pragma unroll
      for (int kk = 0; kk < 2; ++kk)
        af[mi][kk] = *(const short8*)
            &As[(wr * 64 + mi * 16 + lr) * 64 + (((kk * 4 + lg) ^ (lr & 7)) * 8)];
#pragma unroll
    for (int ni = 0; ni < 2; ++ni)
#pragma unroll
      for (int kk = 0; kk < 2; ++kk)
        bf[ni][kk] = *(const short8*)
            &Bs[(wc * 32 + ni * 16 + lr) * 64 + (((kk * 4 + lg) ^ (lr & 7)) * 8)];
#pragma unroll
    for (int mi = 0; mi < 4; ++mi)
#pragma unroll
      for (int ni = 0; ni < 2; ++ni) {
        acc[mi][ni] = MFMA16(af[mi][0], bf[ni][0], acc[mi][ni]);
        acc[mi][ni] = MFMA16(af[mi][1], bf[ni][1], acc[mi][ni]);
      }
    __syncthreads();
  }

  if (MODE == 2 && tn >= 512) {
    // V: LDS-transpose the 128(j) x 64(c) tile, write vtb [bh][c=64][j=512].
    u16* tile = smem;  // [64][136]
#pragma unroll
    for (int mi = 0; mi < 4; ++mi)
#pragma unroll
      for (int ni = 0; ni < 2; ++ni) {
        ushort4 pk;
        pk.x = f2bf(acc[mi][ni][0]); pk.y = f2bf(acc[mi][ni][1]);
        pk.z = f2bf(acc[mi][ni][2]); pk.w = f2bf(acc[mi][ni][3]);
        *(ushort4*)&tile[(wc * 32 + ni * 16 + lr) * 136 + wr * 64 + mi * 16 + lg * 4] = pk;
      }
    __syncthreads();
    int bh = ((tm >> 9) << 3) + ((tn - 512) >> 6);
    u16* dst = (u16*)C1p + (size_t)bh * 64 * 512 + (tm & 511);
#pragma unroll
    for (int p = 0; p < 4; ++p) {
      int c = (p * 256 + t) >> 4, jj = (t & 15) * 8;
      short8 v = *(const short8*)&tile[c * 136 + jj];
      *(short8*)(dst + (size_t)c * 512 + jj) = v;
    }
    return;
  }

#pragma unroll
  for (int mi = 0; mi < 4; ++mi)
#pragma unroll
    for (int ni = 0; ni < 2; ++ni)
#pragma unroll
      for (int r = 0; r < 4; ++r) {
        int rg = tm + wr * 64 + mi * 16 + lg * 4 + r;
        int cg = tn + wc * 32 + ni * 16 + lr;
        float val = acc[mi][ni][r];
        if (MODE == 1) {
          ((u16*)C0p)[(((size_t)(rg >> 11) * 8 + (cg >> 6)) * 2048 + (rg & 2047)) * 64 +
                      (cg & 63)] = f2bf(val);
        } else {
          ((u16*)C0p)[(((size_t)(rg >> 9) * 8 + (cg >> 6)) * 512 + (rg & 511)) * 64 +
                      (cg & 63)] = f2bf(val);
        }
      }
}

// Fused Q + KV projection GEMM (bf16 inputs). 768 blocks: [0,512) Q, [512,768) KV.
__global__ __launch_bounds__(256) void gemm_qkv(const u16* __restrict__ xb,
                                                const u16* __restrict__ wqT,
                                                u16* __restrict__ qhb,
                                                const u16* __restrict__ cb,
                                                const u16* __restrict__ wkvT,
                                                u16* __restrict__ khb,
                                                u16* __restrict__ vtb) {
  __shared__ __align__(16) u16 smem[12288];
  int gid = (int)blockIdx.x;
  gid = (gid & 7) * 96 + (gid >> 3);  // XCD-bijective swizzle (768 % 8 == 0)
  if (gid < 512) {
    gemm_body<1>(xb, wqT, qhb, nullptr, (gid >> 3) * 128, (gid & 7) * 64, 1024, 512, smem);
  } else {
    int g2 = gid - 512;
    gemm_body<2>(cb, wkvT, khb, vtb, (g2 >> 4) * 128, (g2 & 15) * 64, 768, 1024, smem);
  }
}

// ---------------- Output projection GEMM: 128x128 tile ----------------------
// out[8192][1024] = aob[8192][512] * woT[1024][512]^T.  512 blocks (64 M x 8 N),
// 256 threads (4 waves 2x2, 64x64 out each). BK=64: 32 MFMA/wave vs 8 gloads
// per barrier-pair (2x the compute density of the 128x64 tile). 32KB LDS.
__global__ __launch_bounds__(256) void gemm_o(const u16* __restrict__ aob,
                                              const u16* __restrict__ woT,
                                              float* __restrict__ out) {
  __shared__ __align__(16) u16 smem[16384];  // As [128][64] + Bs [128][64]
  u16* As = smem;
  u16* Bs = smem + 8192;
  const int t = threadIdx.x;
  const int w = t >> 6, l = t & 63, lr = l & 15, lg = l >> 4;
  const int wr = w >> 1, wc = w & 1;
  int gid = (int)blockIdx.x;
  gid = (gid & 7) * 64 + (gid >> 3);  // XCD-bijective swizzle (512 % 8 == 0)
  const int tm = (gid >> 3) * 128, tn = (gid & 7) * 128;

  f32x4 acc[4][4];
#pragma unroll
  for (int mi = 0; mi < 4; ++mi)
#pragma unroll
    for (int ni = 0; ni < 4; ++ni) acc[mi][ni] = (f32x4){0.f, 0.f, 0.f, 0.f};

  for (int kt = 0; kt < 512; kt += 64) {
#pragma unroll
    for (int p = 0; p < 4; ++p) {
      int idx = p * 256 + t, row = idx >> 3, cg = idx & 7;
      gload16(aob + (size_t)(tm + row) * 512 + kt + ((cg ^ (row & 7)) * 8),
              As + (p * 256 + (t & 192)) * 8);
    }
#pragma unroll
    for (int p = 0; p < 4; ++p) {
      int idx = p * 256 + t, row = idx >> 3, cg = idx & 7;
      gload16(woT + (size_t)(tn + row) * 512 + kt + ((cg ^ (row & 7)) * 8),
              Bs + (p * 256 + (t & 192)) * 8);
    }
    __syncthreads();
    short8 af[4][2], bf[4][2];
#pragma unroll
    for (int mi = 0; mi < 4; ++mi)
#pragma unroll
      for (int kk = 0; kk < 2; ++kk)
        af[mi][kk] = *(const short8*)
            &As[(wr * 64 + mi * 16 + lr) * 64 + (((kk * 4 + lg) ^ (lr & 7)) * 8)];
#pragma unroll
    for (int ni = 0; ni < 4; ++ni)
#pragma unroll
      for (int kk = 0; kk < 2; ++kk)
        bf[ni][kk] = *(const short8*)
            &Bs[(wc * 64 + ni * 16 + lr) * 64 + (((kk * 4 + lg) ^ (lr & 7)) * 8)];
#pragma unroll
    for (int mi = 0; mi < 4; ++mi)
#pragma unroll
      for (int ni = 0; ni < 4; ++ni) {
        acc[mi][ni] = MFMA16(af[mi][0], bf[ni][0], acc[mi][ni]);
        acc[mi][ni] = MFMA16(af[mi][1], bf[ni][1], acc[mi][ni]);
      }
    __syncthreads();
  }

#pragma unroll
  for (int mi = 0; mi < 4; ++mi)
#pragma unroll
    for (int ni = 0; ni < 4; ++ni)
#pragma unroll
      for (int r = 0; r < 4; ++r)
        out[(size_t)(tm + wr * 64 + mi * 16 + lg * 4 + r) * 1024 + tn + wc * 64 +
            ni * 16 + lr] = acc[mi][ni][r];
}

// ---------------- attention (r14 verified best, verbatim) -------------------
// 512 blocks x 512 threads (8 waves, 16 q-rows each = 128 rows/block).
// K (64KB) and V^T (64KB) staged into separate LDS regions in one batch ->
// ONE __syncthreads; kb/vb read-only afterward, pl wave-private (lgkmcnt +
// sched_barrier fencing). Swapped QK^T, two-pass softmax, cvt_pk P ->
// swizzled LDS -> A-frags, involutive XOR swizzles on kb/vb.
__global__ __launch_bounds__(512, 2) void attn_kernel(const u16* __restrict__ qhb,
                                                      const u16* __restrict__ khb,
                                                      const u16* __restrict__ vtb,
                                                      u16* __restrict__ aob) {
  __shared__ __align__(16) u16 kb[512 * 64];     // K  [512 j][64 c]
  __shared__ __align__(16) u16 vb[64 * 512];     // V^T [64 c][512 j]
  __shared__ __align__(16) u16 pl[8][16 * 64];   // per-wave P window [16 i][64 j]
  const int t = threadIdx.x, w = t >> 6, l = t & 63, i = l & 15, g = l >> 4;
  int lid = (int)blockIdx.x;
  lid = (lid & 7) * 64 + (lid >> 3);  // XCD-bijective swizzle (512 % 8 == 0)
  const int bh = lid >> 4, qh = lid & 15;
  const int i7 = i & 7;
  const int row0 = qh * 128 + w * 16;

  const u16* qp = qhb + ((size_t)bh * 2048 + row0) * 64;
  const u16* kp = khb + (size_t)bh * 512 * 64;
  const u16* vp = vtb + (size_t)bh * 64 * 512;

  short8 qa0 = *(const short8*)(qp + (size_t)i * 64 + g * 8);
  short8 qa1 = *(const short8*)(qp + (size_t)i * 64 + 32 + g * 8);

  const int wbase = (t & 448) * 8;  // wave-uniform LDS chunk base (u16 units)

#pragma unroll
  for (int p = 0; p < 8; ++p) {
    int s = p * 512 + t;
    int r = s >> 3, cg = s & 7;
    gload16(kp + (size_t)r * 64 + ((cg ^ (r & 7)) * 8), kb + p * 4096 + wbase);
  }
#pragma unroll
  for (int p = 0; p < 8; ++p) {
    int s = p * 512 + t;
    int r = s >> 6, cg = s & 63;
    gload16(vp + (size_t)r * 512 + ((cg ^ (r & 7)) * 8), vb + p * 4096 + wbase);
  }
  __syncthreads();  // the ONLY barrier

  // ---- QK^T: all 32 j-tiles, barrier-free ----
  f32x4 sc[32];
#pragma unroll
  for (int jt = 0; jt < 32; ++jt) {
    int r = jt * 16 + i;
    short8 k0 = *(const short8*)&kb[r * 64 + ((g ^ i7) * 8)];
    short8 k1 = *(const short8*)&kb[r * 64 + (((4 + g) ^ i7) * 8)];
    f32x4 a = (f32x4){0.f, 0.f, 0.f, 0.f};
    a = MFMA16(k0, qa0, a);
    a = MFMA16(k1, qa1, a);
    sc[jt] = a;
  }

  // ---- softmax: lane-local over 128 values, then combine 4 g-groups ----
  f32x4 vm = sc[0];
#pragma unroll
  for (int jt = 1; jt < 32; ++jt) {
#pragma unroll
    for (int r = 0; r < 4; ++r) vm[r] = fmaxf(vm[r], sc[jt][r]);
  }
  float mx = fmaxf(fmaxf(vm[0], vm[1]), fmaxf(vm[2], vm[3]));
  mx = fmaxf(mx, __shfl_xor(mx, 16));
  mx = fmaxf(mx, __shfl_xor(mx, 32));
  float sum = 0.f;
#pragma unroll
  for (int jt = 0; jt < 32; ++jt) {
#pragma unroll
    for (int r = 0; r < 4; ++r) {
      float e = __expf(sc[jt][r] - mx);
      sc[jt][r] = e;
      sum += e;
    }
  }
  sum += __shfl_xor(sum, 16);
  sum += __shfl_xor(sum, 32);
  float inv = 1.f / sum;

  // ---- PV: 8 chunks x 2 T-steps, barrier-free (pl wave-private) ----
  u16* pw = pl[w];
  f32x4 oac[4];
#pragma unroll
  for (int ct = 0; ct < 4; ++ct) oac[ct] = (f32x4){0.f, 0.f, 0.f, 0.f};

#pragma unroll
  for (int c8 = 0; c8 < 8; ++c8) {
#pragma unroll
    for (int tt = 0; tt < 4; ++tt) {
      int jt = c8 * 4 + tt;
      unsigned w0, w1;
      asm("v_cvt_pk_bf16_f32 %0, %1, %2" : "=v"(w0) : "v"(sc[jt][0]), "v"(sc[jt][1]));
      asm("v_cvt_pk_bf16_f32 %0, %1, %2" : "=v"(w1) : "v"(sc[jt][2]), "v"(sc[jt][3]));
      uint2 pk2; pk2.x = w0; pk2.y = w1;
      *(uint2*)&pw[i * 64 + ((tt * 16 + g * 4) ^ (i7 * 8))] = pk2;
    }
    asm volatile("s_waitcnt lgkmcnt(0)" ::: "memory");
    __builtin_amdgcn_sched_barrier(0);
#pragma unroll
    for (int T2 = 0; T2 < 2; ++T2) {
      short8 pa = *(const short8*)&pw[i * 64 + ((T2 * 32 + g * 8) ^ (i7 * 8))];
      int jg = c8 * 8 + T2 * 4 + g;  // global j-group 0..63
#pragma unroll
      for (int ct = 0; ct < 4; ++ct) {
        int vr = ct * 16 + i;
        short8 vf = *(const short8*)&vb[vr * 512 + ((jg ^ (vr & 7)) * 8)];
        oac[ct] = MFMA16(pa, vf, oac[ct]);
      }
    }
    asm volatile("" ::: "memory");  // WAR: reads done before next chunk's stores
  }

  // epilogue: redistribute 1/sum to the lanes holding each output row, store.
  float iv[4];
#pragma unroll
  for (int r = 0; r < 4; ++r) iv[r] = __shfl(inv, (l & 48) + g * 4 + r);
  u16* op = aob + ((size_t)(bh >> 3) * 2048 + row0) * 512 + (bh & 7) * 64;
#pragma unroll
  for (int ct = 0; ct < 4; ++ct)
#pragma unroll
    for (int r = 0; r < 4; ++r)
      op[(size_t)(g * 4 + r) * 512 + ct * 16 + i] = f2bf(oac[ct][r] * iv[r]);
}

// ---------------- launch ----------------
extern "C" void kernel_launch(void* const* d_in, const int* in_sizes, int n_in,
                              void* d_out, int out_size, void* d_ws, size_t ws_size,
                              hipStream_t stream) {
  const float* x  = (const float*)d_in[0];  // [4,2048,1024]
  const float* cx = (const float*)d_in[1];  // [4,512,768]
  const float* Wq = (const float*)d_in[2];  // [1024,512]
  const float* Wk = (const float*)d_in[3];  // [768,512]
  const float* Wv = (const float*)d_in[4];  // [768,512]
  const float* Wo = (const float*)d_in[5];  // [512,1024]
  float* out = (float*)d_out;               // [4,2048,1024]

  char* p = (char*)d_ws;
  u16* xb   = (u16*)p; p += (size_t)8388608 * 2;   // x bf16
  u16* cb   = (u16*)p; p += (size_t)1572864 * 2;   // context bf16
  u16* wqT  = (u16*)p; p += (size_t)524288 * 2;    // Wq^T * 0.125   [512][1024]
  u16* wkvT = (u16*)p; p += (size_t)786432 * 2;    // [Wk^T; Wv^T]   [1024][768]
  u16* woT  = (u16*)p; p += (size_t)524288 * 2;    // Wo^T           [1024][512]
  u16* qhb  = (u16*)p; p += (size_t)4194304 * 2;   // q   [bh][2048][64]
  u16* khb  = (u16*)p; p += (size_t)1048576 * 2;   // k   [bh][512][64]
  u16* vtb  = (u16*)p; p += (size_t)1048576 * 2;   // v^T [bh][64][512]
  u16* aob  = (u16*)p; p += (size_t)4194304 * 2;   // attn out [8192][512]

  prep_all<<<dim3(32, 32, 5), dim3(32, 8), 0, stream>>>(
      x, xb, 8388608 / 4, cx, cb, 1572864 / 4, Wq, Wk, Wv, Wo, wqT, wkvT, woT);
  gemm_qkv<<<768, 256, 0, stream>>>(xb, wqT, qhb, cb, wkvT, khb, vtb);
  attn_kernel<<<512, 512, 0, stream>>>(qhb, khb, vtb, aob);
  gemm_o<<<512, 256, 0, stream>>>(aob, woT, out);
}